// Round 1
// baseline (421.530 us; speedup 1.0000x reference)
//
#include <hip/hip_runtime.h>
#include <cstdint>
#include <cstddef>

typedef __bf16 bf16;
typedef __bf16 bf16x4 __attribute__((ext_vector_type(4)));
typedef __bf16 bf16x8 __attribute__((ext_vector_type(8)));
typedef float f32x4 __attribute__((ext_vector_type(4)));

#define B_SZ 1024
#define D_SZ 2048
#define U_SZ 4096
#define BR_SZ 4
#define N_SZ (U_SZ * BR_SZ) /* 16384 */

// workspace layout (bytes)
#define WS_WT 0                        // bf16 [16384][2048] transposed w_mod (64 MiB)
#define WS_A (64u * 1024u * 1024u)     // bf16 [1024][2048] inputs (4 MiB)
#define WS_GAT (WS_A + 4u * 1024u * 1024u)  // f32 [1024][4]
#define WS_CONN (WS_GAT + 16384u)           // f32 [4096]
#define WS_H (WS_CONN + 16384u)             // f32 [32]

__device__ __forceinline__ float sigmoidf_(float x) { return 1.f / (1.f + __expf(-x)); }

// K0: inputs f32 -> bf16, and zero the h-accumulator
__global__ void k0_convert(const float* __restrict__ in, bf16* __restrict__ a,
                           float* __restrict__ wsh) {
  int idx = blockIdx.x * 256 + threadIdx.x;
  if (idx < 32) wsh[idx] = 0.f;
  float4 v = ((const float4*)in)[idx];
  bf16x4 o;
  o[0] = (bf16)v.x; o[1] = (bf16)v.y; o[2] = (bf16)v.z; o[3] = (bf16)v.w;
  ((bf16x4*)a)[idx] = o;
}

// K1: gating = softmax(inputs @ Wg + bg), one block per row
__global__ void k1_gating(const float* __restrict__ in, const float* __restrict__ Wg,
                          const float* __restrict__ bg, float* __restrict__ gat) {
  int row = blockIdx.x, tid = threadIdx.x;
  float a0 = 0, a1 = 0, a2 = 0, a3 = 0;
  const float* ir = in + row * D_SZ;
  for (int d = tid; d < D_SZ; d += 256) {
    float x = ir[d];
    float4 wg = ((const float4*)Wg)[d];
    a0 += x * wg.x; a1 += x * wg.y; a2 += x * wg.z; a3 += x * wg.w;
  }
#pragma unroll
  for (int off = 32; off; off >>= 1) {
    a0 += __shfl_down(a0, off); a1 += __shfl_down(a1, off);
    a2 += __shfl_down(a2, off); a3 += __shfl_down(a3, off);
  }
  __shared__ float red[4][4];
  int wv = tid >> 6, ln = tid & 63;
  if (ln == 0) { red[wv][0] = a0; red[wv][1] = a1; red[wv][2] = a2; red[wv][3] = a3; }
  __syncthreads();
  if (tid == 0) {
    float s0 = red[0][0] + red[1][0] + red[2][0] + red[3][0] + bg[0];
    float s1 = red[0][1] + red[1][1] + red[2][1] + red[3][1] + bg[1];
    float s2 = red[0][2] + red[1][2] + red[2][2] + red[3][2] + bg[2];
    float s3 = red[0][3] + red[1][3] + red[2][3] + red[3][3] + bg[3];
    float m = fmaxf(fmaxf(s0, s1), fmaxf(s2, s3));
    float e0 = __expf(s0 - m), e1 = __expf(s1 - m), e2 = __expf(s2 - m), e3 = __expf(s3 - m);
    float inv = 1.f / (e0 + e1 + e2 + e3);
    ((float4*)gat)[row] = make_float4(e0 * inv, e1 * inv, e2 * inv, e3 * inv);
  }
}

// K2a: h_partial = avg @ W1 (atomic accumulate into wsh[32])
__global__ void k2a_h(const float* __restrict__ avg, const float* __restrict__ W1,
                      float* __restrict__ wsh) {
  int t = threadIdx.x;
  int h = t & 31, seg = t >> 5;
  int u0 = blockIdx.x * 64 + seg * 8;
  float p = 0.f;
#pragma unroll
  for (int j = 0; j < 8; j++) {
    int u = u0 + j;
    p += avg[u] * W1[u * 32 + h];
  }
  __shared__ float red[8][32];
  red[seg][h] = p;
  __syncthreads();
  if (t < 32) {
    float s = 0.f;
#pragma unroll
    for (int sg = 0; sg < 8; sg++) s += red[sg][t];
    atomicAdd(&wsh[t], s);
  }
}

// K2b: conn[u] = sigmoid(relu(h + b1) @ W2 + b2) * mask[u]
__global__ void k2b_conn(const float* __restrict__ wsh, const float* __restrict__ b1,
                         const float* __restrict__ W2, const float* __restrict__ b2,
                         const float* __restrict__ mask, float* __restrict__ conn) {
  int u = blockIdx.x * 256 + threadIdx.x;
  __shared__ float hv[32];
  if (threadIdx.x < 32) hv[threadIdx.x] = fmaxf(wsh[threadIdx.x] + b1[threadIdx.x], 0.f);
  __syncthreads();
  float s = b2[u];
#pragma unroll
  for (int h = 0; h < 32; h++) s += hv[h] * W2[h * U_SZ + u];
  conn[u] = sigmoidf_(s) * mask[u];
}

// K3: wT[n][d] = bf16(w[d][n] * sigmoid(delay[d][n])) — 64x64 tiles via LDS
#define TP 72
__global__ void k3_wmod_t(const float* __restrict__ w, const float* __restrict__ delay,
                          bf16* __restrict__ wt) {
  __shared__ bf16 t[64 * TP];
  int tid = threadIdx.x;
  int n0 = blockIdx.x * 64, d0 = blockIdx.y * 64;
#pragma unroll
  for (int i = 0; i < 4; i++) {
    int flat = i * 256 + tid;
    int d = flat >> 4, n4 = flat & 15;
    int gi = (d0 + d) * N_SZ + n0 + n4 * 4;
    float4 wv = *(const float4*)(w + gi);
    float4 dv = *(const float4*)(delay + gi);
    t[(n4 * 4 + 0) * TP + d] = (bf16)(wv.x * sigmoidf_(dv.x));
    t[(n4 * 4 + 1) * TP + d] = (bf16)(wv.y * sigmoidf_(dv.y));
    t[(n4 * 4 + 2) * TP + d] = (bf16)(wv.z * sigmoidf_(dv.z));
    t[(n4 * 4 + 3) * TP + d] = (bf16)(wv.w * sigmoidf_(dv.w));
  }
  __syncthreads();
#pragma unroll
  for (int p = 0; p < 2; p++) {
    int flat = p * 256 + tid;
    int n = flat >> 3, d8 = flat & 7;
    bf16x8 v = *(const bf16x8*)&t[n * TP + d8 * 8];
    *(bf16x8*)(wt + (size_t)(n0 + n) * D_SZ + d0 + d8 * 8) = v;
  }
}

// K4: GEMM [1024,2048]x[2048,16384] bf16 MFMA, epilogue: +bias, gating-contract
// over BR=4, *conn*mask, relu -> out [1024][4096] f32
__global__ __launch_bounds__(256, 2) void k4_gemm(
    const bf16* __restrict__ A, const bf16* __restrict__ Bt,
    const float* __restrict__ gating, const float* __restrict__ bias,
    const float* __restrict__ conn, float* __restrict__ out) {
  __shared__ bf16 Al[128 * 64];
  __shared__ bf16 Bl[128 * 64];
  __shared__ float gat[128 * 4];
  int tid = threadIdx.x;
  int lane = tid & 63, wave = tid >> 6;
  int bid = blockIdx.x;
  int mt = bid & 7, nt = bid >> 3;
  int m0 = mt * 128, n0 = nt * 128;
  int wm = (wave & 1) * 64, wn = (wave >> 1) * 64;
  int quad = lane >> 4, row16 = lane & 15;

  f32x4 acc[4][4];
  const f32x4 z4 = {0.f, 0.f, 0.f, 0.f};
#pragma unroll
  for (int i = 0; i < 4; i++)
#pragma unroll
    for (int j = 0; j < 4; j++) acc[i][j] = z4;

  if (tid < 128) *(float4*)&gat[tid * 4] = *(const float4*)&gating[(m0 + tid) * 4];

  int srow = lane >> 3, scol = (lane & 7) * 8;
  for (int kt = 0; kt < 32; kt++) {
    int k0 = kt * 64;
#pragma unroll
    for (int c = 0; c < 4; c++) {
      int rb = wave * 32 + c * 8;
      const bf16* ga = A + (size_t)(m0 + rb + srow) * D_SZ + k0 + scol;
      __builtin_amdgcn_global_load_lds(
          (const __attribute__((address_space(1))) void*)ga,
          (__attribute__((address_space(3))) void*)(Al + rb * 64), 16, 0, 0);
      const bf16* gb = Bt + (size_t)(n0 + rb + srow) * D_SZ + k0 + scol;
      __builtin_amdgcn_global_load_lds(
          (const __attribute__((address_space(1))) void*)gb,
          (__attribute__((address_space(3))) void*)(Bl + rb * 64), 16, 0, 0);
    }
    __syncthreads();
#pragma unroll
    for (int kk = 0; kk < 64; kk += 32) {
      bf16x8 af[4], bfr[4];
#pragma unroll
      for (int i = 0; i < 4; i++)
        af[i] = *(const bf16x8*)&Al[(wm + i * 16 + row16) * 64 + kk + quad * 8];
#pragma unroll
      for (int j = 0; j < 4; j++)
        bfr[j] = *(const bf16x8*)&Bl[(wn + j * 16 + row16) * 64 + kk + quad * 8];
#pragma unroll
      for (int i = 0; i < 4; i++)
#pragma unroll
        for (int j = 0; j < 4; j++)
          acc[i][j] = __builtin_amdgcn_mfma_f32_16x16x32_bf16(af[i], bfr[j], acc[i][j], 0, 0, 0);
    }
    __syncthreads();
  }

  // epilogue: C layout col=lane&15, row=quad*4+reg. n = u*4+k, k = lane&3.
  int k = lane & 3;
#pragma unroll
  for (int j = 0; j < 4; j++) {
    int n_l = wn + j * 16 + row16;
    int n_g = n0 + n_l;
    int u = n_g >> 2;
    float bv = bias[n_g];
    float cv = conn[u];
#pragma unroll
    for (int i = 0; i < 4; i++) {
#pragma unroll
      for (int r = 0; r < 4; r++) {
        int r_l = wm + i * 16 + quad * 4 + r;
        float g = gat[r_l * 4 + k];
        float v = (acc[i][j][r] + bv) * g;
        v += __shfl_xor(v, 1);
        v += __shfl_xor(v, 2);
        if (k == 0) out[(size_t)(m0 + r_l) * U_SZ + u] = fmaxf(v * cv, 0.f);
      }
    }
  }
}

extern "C" void kernel_launch(void* const* d_in, const int* in_sizes, int n_in,
                              void* d_out, int out_size, void* d_ws, size_t ws_size,
                              hipStream_t stream) {
  const float* inputs = (const float*)d_in[0];
  const float* w = (const float*)d_in[1];
  const float* bb = (const float*)d_in[2];
  const float* delay = (const float*)d_in[3];
  const float* Wg = (const float*)d_in[4];
  const float* bg = (const float*)d_in[5];
  const float* W1 = (const float*)d_in[6];
  const float* b1 = (const float*)d_in[7];
  const float* W2 = (const float*)d_in[8];
  const float* b2 = (const float*)d_in[9];
  const float* mask = (const float*)d_in[10];
  const float* avg = (const float*)d_in[11];
  float* out = (float*)d_out;
  char* ws = (char*)d_ws;
  bf16* wt = (bf16*)(ws + WS_WT);
  bf16* wa = (bf16*)(ws + WS_A);
  float* gat = (float*)(ws + WS_GAT);
  float* cn = (float*)(ws + WS_CONN);
  float* wsh = (float*)(ws + WS_H);

  hipLaunchKernelGGL(k0_convert, dim3((B_SZ * D_SZ / 4) / 256), dim3(256), 0, stream, inputs, wa, wsh);
  hipLaunchKernelGGL(k1_gating, dim3(B_SZ), dim3(256), 0, stream, inputs, Wg, bg, gat);
  hipLaunchKernelGGL(k2a_h, dim3(U_SZ / 64), dim3(256), 0, stream, avg, W1, wsh);
  hipLaunchKernelGGL(k2b_conn, dim3(U_SZ / 256), dim3(256), 0, stream, wsh, b1, W2, b2, mask, cn);
  hipLaunchKernelGGL(k3_wmod_t, dim3(N_SZ / 64, D_SZ / 64), dim3(256), 0, stream, w, delay, wt);
  hipLaunchKernelGGL(k4_gemm, dim3((B_SZ / 128) * (N_SZ / 128)), dim3(256), 0, stream, wa, wt, gat, bb, cn, out);
}

// Round 2
// 389.559 us; speedup vs baseline: 1.0821x; 1.0821x over previous
//
#include <hip/hip_runtime.h>
#include <cstdint>
#include <cstddef>

typedef __bf16 bf16;
typedef __bf16 bf16x4 __attribute__((ext_vector_type(4)));
typedef __bf16 bf16x8 __attribute__((ext_vector_type(8)));
typedef float f32x4 __attribute__((ext_vector_type(4)));

#define B_SZ 1024
#define D_SZ 2048
#define U_SZ 4096
#define BR_SZ 4
#define N_SZ (U_SZ * BR_SZ) /* 16384 */

// workspace layout (bytes)
#define WS_WT 0                            // bf16 [16384][2048] transposed w_mod (64 MiB)
#define WS_A (64u * 1024u * 1024u)         // bf16 [1024][2048] inputs (4 MiB)
#define WS_GAT (WS_A + 4u * 1024u * 1024u) // f32 [1024][4]
#define WS_H (WS_GAT + 16384u)             // f32 [32]

__device__ __forceinline__ float sigmoidf_(float x) { return 1.f / (1.f + __expf(-x)); }

__device__ __forceinline__ uint32_t pack2_(float lo, float hi) {
  union { bf16 h[2]; uint32_t u; } cv;
  cv.h[0] = (bf16)lo; cv.h[1] = (bf16)hi;
  return cv.u;
}

// K01: inputs f32 -> bf16 + gating softmax, one block per row; block0 zeroes wsh
__global__ void k01_prep(const float* __restrict__ in, bf16* __restrict__ wa,
                         const float* __restrict__ Wg, const float* __restrict__ bg,
                         float* __restrict__ gat, float* __restrict__ wsh) {
  int row = blockIdx.x, tid = threadIdx.x;
  if (row == 0 && tid < 32) wsh[tid] = 0.f;
  const float* ir = in + (size_t)row * D_SZ;
  float a0 = 0, a1 = 0, a2 = 0, a3 = 0;
#pragma unroll
  for (int c = 0; c < 2; c++) {
    int d = c * 1024 + tid * 4;
    float4 x = *(const float4*)(ir + d);
    bf16x4 o;
    o[0] = (bf16)x.x; o[1] = (bf16)x.y; o[2] = (bf16)x.z; o[3] = (bf16)x.w;
    *(bf16x4*)(wa + (size_t)row * D_SZ + d) = o;
    const float xs[4] = {x.x, x.y, x.z, x.w};
#pragma unroll
    for (int j = 0; j < 4; j++) {
      float4 wg = ((const float4*)Wg)[d + j];
      a0 += xs[j] * wg.x; a1 += xs[j] * wg.y; a2 += xs[j] * wg.z; a3 += xs[j] * wg.w;
    }
  }
#pragma unroll
  for (int off = 32; off; off >>= 1) {
    a0 += __shfl_down(a0, off); a1 += __shfl_down(a1, off);
    a2 += __shfl_down(a2, off); a3 += __shfl_down(a3, off);
  }
  __shared__ float red[4][4];
  int wv = tid >> 6, ln = tid & 63;
  if (ln == 0) { red[wv][0] = a0; red[wv][1] = a1; red[wv][2] = a2; red[wv][3] = a3; }
  __syncthreads();
  if (tid == 0) {
    float s0 = red[0][0] + red[1][0] + red[2][0] + red[3][0] + bg[0];
    float s1 = red[0][1] + red[1][1] + red[2][1] + red[3][1] + bg[1];
    float s2 = red[0][2] + red[1][2] + red[2][2] + red[3][2] + bg[2];
    float s3 = red[0][3] + red[1][3] + red[2][3] + red[3][3] + bg[3];
    float m = fmaxf(fmaxf(s0, s1), fmaxf(s2, s3));
    float e0 = __expf(s0 - m), e1 = __expf(s1 - m), e2 = __expf(s2 - m), e3 = __expf(s3 - m);
    float inv = 1.f / (e0 + e1 + e2 + e3);
    ((float4*)gat)[row] = make_float4(e0 * inv, e1 * inv, e2 * inv, e3 * inv);
  }
}

// K2a: h_partial = avg @ W1 (atomic accumulate into wsh[32])
__global__ void k2a_h(const float* __restrict__ avg, const float* __restrict__ W1,
                      float* __restrict__ wsh) {
  int t = threadIdx.x;
  int h = t & 31, seg = t >> 5;
  int u0 = blockIdx.x * 64 + seg * 8;
  float p = 0.f;
#pragma unroll
  for (int j = 0; j < 8; j++) {
    int u = u0 + j;
    p += avg[u] * W1[u * 32 + h];
  }
  __shared__ float red[8][32];
  red[seg][h] = p;
  __syncthreads();
  if (t < 32) {
    float s = 0.f;
#pragma unroll
    for (int sg = 0; sg < 8; sg++) s += red[sg][t];
    atomicAdd(&wsh[t], s);
  }
}

// K3: wT[n][d] = bf16(w[d][n]*sigmoid(delay[d][n])). d-pairs packed in dwords;
// pitch 33 dwords (==1 mod 32) -> all LDS ops <=2-way banked (free). 4 tiles
// (64n x 64d each) per block, double-buffered LDS, 1 barrier/tile.
#define K3P 33
__global__ __launch_bounds__(256) void k3_wmod_t(const float* __restrict__ w,
                                                 const float* __restrict__ delay,
                                                 bf16* __restrict__ wt) {
  __shared__ uint32_t buf[2][64 * K3P];
  int tid = threadIdx.x;
  int n0 = blockIdx.x * 64;
  int d0 = blockIdx.y * 256;
  int d2 = tid >> 4, n4 = tid & 15;      // phase1: 16 d-pairs x 16 n4 per pass
  int p2n = tid >> 3, p2o = tid & 7;     // phase2: 32 n x 8 d-octets per pass

  float4 rw[4], rd[4];

  // ---- load regs for tile t ----
#define K3_LOAD(t)                                                         \
  {                                                                        \
    _Pragma("unroll") for (int pass = 0; pass < 2; pass++) {               \
      int d = d0 + (t) * 64 + pass * 32 + d2 * 2;                          \
      size_t g = (size_t)d * N_SZ + n0 + n4 * 4;                           \
      rw[pass * 2 + 0] = *(const float4*)(w + g);                          \
      rw[pass * 2 + 1] = *(const float4*)(w + g + N_SZ);                   \
      rd[pass * 2 + 0] = *(const float4*)(delay + g);                      \
      rd[pass * 2 + 1] = *(const float4*)(delay + g + N_SZ);               \
    }                                                                      \
  }
  // ---- sigmoid*w, pack pairs, write LDS ----
#define K3_WRITE(bsel)                                                     \
  {                                                                        \
    _Pragma("unroll") for (int pass = 0; pass < 2; pass++) {               \
      const float* fw0 = (const float*)&rw[pass * 2 + 0];                  \
      const float* fw1 = (const float*)&rw[pass * 2 + 1];                  \
      const float* fd0 = (const float*)&rd[pass * 2 + 0];                  \
      const float* fd1 = (const float*)&rd[pass * 2 + 1];                  \
      _Pragma("unroll") for (int j = 0; j < 4; j++) {                      \
        float lo = fw0[j] * sigmoidf_(fd0[j]);                             \
        float hi = fw1[j] * sigmoidf_(fd1[j]);                             \
        buf[bsel][(n4 * 4 + j) * K3P + pass * 16 + d2] = pack2_(lo, hi);   \
      }                                                                    \
    }                                                                      \
  }
  // ---- read LDS columns, store transposed to global ----
#define K3_STORE(t, bsel)                                                  \
  {                                                                        \
    int dt = d0 + (t) * 64;                                                \
    _Pragma("unroll") for (int pass = 0; pass < 2; pass++) {               \
      int n = pass * 32 + p2n;                                             \
      const uint32_t* r = &buf[bsel][n * K3P + p2o * 4];                   \
      uint4 v;                                                             \
      v.x = r[0]; v.y = r[1]; v.z = r[2]; v.w = r[3];                      \
      *(uint4*)(wt + (size_t)(n0 + n) * D_SZ + dt + p2o * 8) = v;          \
    }                                                                      \
  }

  K3_LOAD(0);
  K3_WRITE(0);
#pragma unroll
  for (int t = 0; t < 4; t++) {
    __syncthreads();
    if (t < 3) K3_LOAD(t + 1);
    K3_STORE(t, (t & 1));
    if (t < 3) K3_WRITE(((t + 1) & 1));
  }
}

// K4: GEMM [1024,2048]x[2048,16384] bf16 MFMA. XOR-swizzled LDS chunks
// (2-way banks on fragment reads), XCD-aware bid swizzle (B-tile L2 locality).
// Epilogue: +bias, gating-contract over BR=4, connectivity-MLP, mask, relu.
__global__ __launch_bounds__(256, 2) void k4_gemm(
    const bf16* __restrict__ A, const bf16* __restrict__ Bt,
    const float* __restrict__ gating, const float* __restrict__ bias,
    const float* __restrict__ wsh, const float* __restrict__ b1,
    const float* __restrict__ W2, const float* __restrict__ b2,
    const float* __restrict__ mask, float* __restrict__ out) {
  __shared__ bf16 Al[128 * 64];
  __shared__ bf16 Bl[128 * 64];
  __shared__ float gat[128 * 4];
  __shared__ float conn_l[32];
  int tid = threadIdx.x;
  int lane = tid & 63, wave = tid >> 6;
  // XCD swizzle: bid%8 = XCD; each XCD owns 16 nt columns, iterates mt fastest
  int bid = blockIdx.x;
  int xcd = bid & 7, p = bid >> 3;
  int mt = p & 7, nt = (xcd << 4) | (p >> 3);
  int m0 = mt * 128, n0 = nt * 128;
  int wm = (wave & 1) * 64, wn = (wave >> 1) * 64;
  int quad = lane >> 4, row16 = lane & 15;
  int r7 = row16 & 7;

  f32x4 acc[4][4];
  const f32x4 z4 = {0.f, 0.f, 0.f, 0.f};
#pragma unroll
  for (int i = 0; i < 4; i++)
#pragma unroll
    for (int j = 0; j < 4; j++) acc[i][j] = z4;

  if (tid < 128) *(float4*)&gat[tid * 4] = *(const float4*)&gating[(m0 + tid) * 4];
  if (tid < 32) {
    int u = (n0 >> 2) + tid;
    float s = b2[u];
#pragma unroll
    for (int h = 0; h < 32; h++) s += fmaxf(wsh[h] + b1[h], 0.f) * W2[h * U_SZ + u];
    conn_l[tid] = sigmoidf_(s) * mask[u];
  }

  int srow = lane >> 3;
  int scol = ((lane & 7) ^ srow) * 8;  // XOR-swizzled 16B chunk
  for (int kt = 0; kt < 32; kt++) {
    int k0 = kt * 64;
#pragma unroll
    for (int c = 0; c < 4; c++) {
      int rb = wave * 32 + c * 8;
      const bf16* ga = A + (size_t)(m0 + rb + srow) * D_SZ + k0 + scol;
      __builtin_amdgcn_global_load_lds(
          (const __attribute__((address_space(1))) void*)ga,
          (__attribute__((address_space(3))) void*)(Al + rb * 64), 16, 0, 0);
      const bf16* gb = Bt + (size_t)(n0 + rb + srow) * D_SZ + k0 + scol;
      __builtin_amdgcn_global_load_lds(
          (const __attribute__((address_space(1))) void*)gb,
          (__attribute__((address_space(3))) void*)(Bl + rb * 64), 16, 0, 0);
    }
    __syncthreads();
#pragma unroll
    for (int kk = 0; kk < 64; kk += 32) {
      int csw = (((kk >> 3) + quad) ^ r7) * 8;  // un-swizzle chunk
      bf16x8 af[4], bfr[4];
#pragma unroll
      for (int i = 0; i < 4; i++)
        af[i] = *(const bf16x8*)&Al[(wm + i * 16 + row16) * 64 + csw];
#pragma unroll
      for (int j = 0; j < 4; j++)
        bfr[j] = *(const bf16x8*)&Bl[(wn + j * 16 + row16) * 64 + csw];
#pragma unroll
      for (int i = 0; i < 4; i++)
#pragma unroll
        for (int j = 0; j < 4; j++)
          acc[i][j] = __builtin_amdgcn_mfma_f32_16x16x32_bf16(af[i], bfr[j], acc[i][j], 0, 0, 0);
    }
    __syncthreads();
  }

  // epilogue: C layout col=lane&15, row=quad*4+reg. n = u*4+k, k = lane&3.
  int k = lane & 3;
#pragma unroll
  for (int j = 0; j < 4; j++) {
    int n_l = wn + j * 16 + row16;
    int n_g = n0 + n_l;
    int u = n_g >> 2;
    float bv = bias[n_g];
    float cv = conn_l[n_l >> 2];
#pragma unroll
    for (int i = 0; i < 4; i++) {
#pragma unroll
      for (int r = 0; r < 4; r++) {
        int r_l = wm + i * 16 + quad * 4 + r;
        float g = gat[r_l * 4 + k];
        float v = (acc[i][j][r] + bv) * g;
        v += __shfl_xor(v, 1);
        v += __shfl_xor(v, 2);
        if (k == 0) out[(size_t)(m0 + r_l) * U_SZ + u] = fmaxf(v * cv, 0.f);
      }
    }
  }
}

extern "C" void kernel_launch(void* const* d_in, const int* in_sizes, int n_in,
                              void* d_out, int out_size, void* d_ws, size_t ws_size,
                              hipStream_t stream) {
  const float* inputs = (const float*)d_in[0];
  const float* w = (const float*)d_in[1];
  const float* bb = (const float*)d_in[2];
  const float* delay = (const float*)d_in[3];
  const float* Wg = (const float*)d_in[4];
  const float* bg = (const float*)d_in[5];
  const float* W1 = (const float*)d_in[6];
  const float* b1 = (const float*)d_in[7];
  const float* W2 = (const float*)d_in[8];
  const float* b2 = (const float*)d_in[9];
  const float* mask = (const float*)d_in[10];
  const float* avg = (const float*)d_in[11];
  float* out = (float*)d_out;
  char* ws = (char*)d_ws;
  bf16* wt = (bf16*)(ws + WS_WT);
  bf16* wa = (bf16*)(ws + WS_A);
  float* gat = (float*)(ws + WS_GAT);
  float* wsh = (float*)(ws + WS_H);

  hipLaunchKernelGGL(k01_prep, dim3(B_SZ), dim3(256), 0, stream, inputs, wa, Wg, bg, gat, wsh);
  hipLaunchKernelGGL(k2a_h, dim3(U_SZ / 64), dim3(256), 0, stream, avg, W1, wsh);
  hipLaunchKernelGGL(k3_wmod_t, dim3(N_SZ / 64, D_SZ / 256), dim3(256), 0, stream, w, delay, wt);
  hipLaunchKernelGGL(k4_gemm, dim3((B_SZ / 128) * (N_SZ / 128)), dim3(256), 0, stream, wa, wt, gat, bb, wsh, b1, W2, b2, mask, out);
}